// Round 9
// baseline (105.232 us; speedup 1.0000x reference)
//
#include <hip/hip_runtime.h>

#define Bb 64
#define Ll 32
#define Hh 128
#define Oo 16384
#define Cc 32

// ws (floats): A[8192] | SA2w[64] | w2h[128] | w1t[4096] | gcoef[256] | pad | g_t[Hh*Oo]

// ---------------------------------------------------------------------------
// prep: A = relu(z@Wz+bz)@W1[:H];  SA2w[b] = b2 + sum 0.5*W2*A[b,:]
// side: w1t = W1_f^T (h-major), w2h = 0.5*W2, gcoef[h] = {w1b[h], b1[h]}
// ---------------------------------------------------------------------------
__global__ __launch_bounds__(256) void prep_kernel(
    const float* __restrict__ z, const float* __restrict__ Wz,
    const float* __restrict__ bz, const float* __restrict__ W1,
    const float* __restrict__ b1, const float* __restrict__ W2,
    const float* __restrict__ b2,
    float* __restrict__ A, float* __restrict__ SA2w,
    float* __restrict__ w2h, float* __restrict__ w1t,
    float* __restrict__ gcoef)
{
    __shared__ float pz[2][Hh];
    __shared__ float ps[2][Hh];
    const int t  = threadIdx.x;
    const int h  = t & (Hh - 1);
    const int bb = t >> 7;
    const int b  = blockIdx.x * 2 + bb;

    float v = bz[h];
#pragma unroll
    for (int c = 0; c < Ll; ++c)
        v = fmaf(z[b * Ll + c], Wz[c * Hh + h], v);
    pz[bb][h] = fmaxf(v, 0.f);
    __syncthreads();

    float a = 0.f;
#pragma unroll
    for (int k = 0; k < Hh; ++k)
        a = fmaf(pz[bb][k], W1[k * Hh + h], a);
    A[b * Hh + h] = a;
    ps[bb][h] = 0.5f * W2[h] * a;
    __syncthreads();

    if (h == 0) {
        float s = b2[0];
        for (int k = 0; k < Hh; ++k) s += ps[bb][k];
        SA2w[b] = s;
    }

    // side work (each of 32 blocks handles 4 h-columns)
    if (t < 128) {
        const int h2 = blockIdx.x * 4 + (t >> 5);
        const int c  = t & 31;
        w1t[h2 * Cc + c] = W1[(Hh + c) * Hh + h2];
    }
    if (t < 4) {
        const int h2 = blockIdx.x * 4 + t;
        w2h[h2] = 0.5f * W2[h2];
        gcoef[2 * h2 + 0] = W1[(Hh + Cc) * Hh + h2];
        gcoef[2 * h2 + 1] = b1[h2];
    }
}

// ---------------------------------------------------------------------------
// g_kernel: g_t[h][o] = fe[o,:]@W1_f[:,h] + fb[o]*w1b[h] + b1[h]   (h-major)
// 512 blocks x 256 thr, no LDS/sync. lane = o, fe row in 32 VGPRs;
// w1t/gcoef via uniform s_load (same rows for all blocks -> K$-hot).
// ---------------------------------------------------------------------------
__global__ __launch_bounds__(256) void g_kernel(
    const float* __restrict__ fe, const float* __restrict__ fb,
    const float* __restrict__ w1t, const float* __restrict__ gcoef,
    float* __restrict__ g_t)
{
    const int t    = threadIdx.x;
    const int lane = t & 63;
    const int wave = t >> 6;
    const int o    = (blockIdx.x & 255) * 64 + lane;
    const int hb   = (blockIdx.x >> 8) * 64 + wave * 16;   // 16 h per wave

    float4 fer[8];
    const float4* fep = (const float4*)(fe + o * Cc);
#pragma unroll
    for (int k = 0; k < 8; ++k) fer[k] = fep[k];
    const float fbv = fb[o];

#pragma unroll 2
    for (int j = 0; j < 8; ++j) {                  // 2 h per iter
        const int h = hb + 2 * j;
        const float* __restrict__ wt0 = w1t + (h + 0) * Cc;   // uniform
        const float* __restrict__ wt1 = w1t + (h + 1) * Cc;   // uniform
        float g0 = fmaf(fbv, gcoef[2 * h + 0], gcoef[2 * h + 1]);
        float g1 = fmaf(fbv, gcoef[2 * h + 2], gcoef[2 * h + 3]);
#pragma unroll
        for (int k = 0; k < 8; ++k) {
            g0 = fmaf(fer[k].x, wt0[4 * k + 0], g0);
            g0 = fmaf(fer[k].y, wt0[4 * k + 1], g0);
            g0 = fmaf(fer[k].z, wt0[4 * k + 2], g0);
            g0 = fmaf(fer[k].w, wt0[4 * k + 3], g0);
            g1 = fmaf(fer[k].x, wt1[4 * k + 0], g1);
            g1 = fmaf(fer[k].y, wt1[4 * k + 1], g1);
            g1 = fmaf(fer[k].z, wt1[4 * k + 2], g1);
            g1 = fmaf(fer[k].w, wt1[4 * k + 3], g1);
        }
        g_t[(h + 0) * Oo + o] = g0;                // coalesced dword
        g_t[(h + 1) * Oo + o] = g1;
    }
}

// ---------------------------------------------------------------------------
// m_kernel: out[b,o] = SA2w[b] + sg[o] + sum_h w2h[h]*|A[b,h]+g[o,h]|
// REGISTER-TILED: each thread computes 4 b x 2 o.
// 512 blocks x 256 thr (2/CU), no LDS, no sync.
//   bid: ogrp = bid & 31 (512-o range), bgrp = bid >> 5 (4 b-rows).
// Per 4-h chunk: 4x dwordx2 g (coalesced) + 4x s_load_dwordx4 A (uniform,
// blockIdx-derived) + 1x dwordx4 w2 -> 72 VALU. Ratio ~8 VALU/delivery.
// ---------------------------------------------------------------------------
__global__ __launch_bounds__(256) void m_kernel(
    const float* __restrict__ A, const float* __restrict__ SA2w,
    const float* __restrict__ w2h, const float* __restrict__ g_t,
    float* __restrict__ out)
{
    const int t  = threadIdx.x;
    const int o  = (blockIdx.x & 31) * 512 + 2 * t;       // o-pair base
    const int b0 = (blockIdx.x >> 5) * 4;                 // uniform

    const float* __restrict__ A0 = A + (b0 + 0) * Hh;     // uniform rows
    const float* __restrict__ A1 = A + (b0 + 1) * Hh;
    const float* __restrict__ A2 = A + (b0 + 2) * Hh;
    const float* __restrict__ A3 = A + (b0 + 3) * Hh;

    float acc[4][2];
#pragma unroll
    for (int bi = 0; bi < 4; ++bi) { acc[bi][0] = 0.f; acc[bi][1] = 0.f; }
    float sg0 = 0.f, sg1 = 0.f;

#pragma unroll 2
    for (int hc = 0; hc < 32; ++hc) {                     // 4 h per chunk
        const int h = 4 * hc;
        float2 g[4];
#pragma unroll
        for (int j = 0; j < 4; ++j)                       // coalesced dwordx2
            g[j] = *(const float2*)(g_t + (h + j) * Oo + o);
        const float4 w4 = *(const float4*)(w2h + h);      // uniform s_load
        const float4 a0 = *(const float4*)(A0 + h);       // uniform s_load
        const float4 a1 = *(const float4*)(A1 + h);
        const float4 a2 = *(const float4*)(A2 + h);
        const float4 a3 = *(const float4*)(A3 + h);
#pragma unroll
        for (int j = 0; j < 4; ++j) {
            const float wj  = (&w4.x)[j];
            const float gx  = g[j].x, gy = g[j].y;
            sg0 = fmaf(wj, gx, sg0);
            sg1 = fmaf(wj, gy, sg1);
            const float e0 = (&a0.x)[j], e1 = (&a1.x)[j];
            const float e2 = (&a2.x)[j], e3 = (&a3.x)[j];
            acc[0][0] = fmaf(__builtin_fabsf(e0 + gx), wj, acc[0][0]);
            acc[0][1] = fmaf(__builtin_fabsf(e0 + gy), wj, acc[0][1]);
            acc[1][0] = fmaf(__builtin_fabsf(e1 + gx), wj, acc[1][0]);
            acc[1][1] = fmaf(__builtin_fabsf(e1 + gy), wj, acc[1][1]);
            acc[2][0] = fmaf(__builtin_fabsf(e2 + gx), wj, acc[2][0]);
            acc[2][1] = fmaf(__builtin_fabsf(e2 + gy), wj, acc[2][1]);
            acc[3][0] = fmaf(__builtin_fabsf(e3 + gx), wj, acc[3][0]);
            acc[3][1] = fmaf(__builtin_fabsf(e3 + gy), wj, acc[3][1]);
        }
    }

#pragma unroll
    for (int bi = 0; bi < 4; ++bi) {
        const float s = SA2w[b0 + bi];                    // uniform s_load
        const float2 r = make_float2(acc[bi][0] + sg0 + s,
                                     acc[bi][1] + sg1 + s);
        *(float2*)(out + (b0 + bi) * Oo + o) = r;         // coalesced dwordx2
    }
}

extern "C" void kernel_launch(void* const* d_in, const int* in_sizes, int n_in,
                              void* d_out, int out_size, void* d_ws, size_t ws_size,
                              hipStream_t stream) {
    (void)in_sizes; (void)n_in; (void)out_size; (void)ws_size;
    const float* z   = (const float*)d_in[0];   // (64,32)
    const float* fe  = (const float*)d_in[1];   // (16384,32)
    const float* fb  = (const float*)d_in[2];   // (16384,1)
    const float* Wz  = (const float*)d_in[3];   // (32,128)
    const float* bz  = (const float*)d_in[4];   // (128,)
    const float* W1  = (const float*)d_in[5];   // (161,128)
    const float* b1  = (const float*)d_in[6];   // (128,)
    const float* W2  = (const float*)d_in[7];   // (128,1)
    const float* b2  = (const float*)d_in[8];   // (1,)
    float* out   = (float*)d_out;               // (64,16384)
    float* A     = (float*)d_ws;                // 8192
    float* SA2w  = A + Bb * Hh;                 // 64
    float* w2h   = SA2w + Bb;                   // 128
    float* w1t   = w2h + Hh;                    // 4096
    float* gcoef = w1t + Hh * Cc;               // 256
    float* g_t   = (float*)d_ws + 16384;        // Hh*Oo floats

    prep_kernel<<<Bb / 2, 256, 0, stream>>>(z, Wz, bz, W1, b1, W2, b2,
                                            A, SA2w, w2h, w1t, gcoef);
    g_kernel<<<512, 256, 0, stream>>>(fe, fb, w1t, gcoef, g_t);
    m_kernel<<<512, 256, 0, stream>>>(A, SA2w, w2h, g_t, out);
}

// Round 10
// 92.901 us; speedup vs baseline: 1.1327x; 1.1327x over previous
//
#include <hip/hip_runtime.h>

#define Bb 64
#define Ll 32
#define Hh 128
#define Oo 16384
#define Cc 32
#define TOo 64
#define NT 1024

// ws (floats): A[8192] | SA2w[64] | w2h[128] | w1t[4096] | gcoef[256]

// ---------------------------------------------------------------------------
// prep: A = relu(z@Wz+bz)@W1[:H];  SA2w[b] = b2 + sum 0.5*W2*A[b,:]
// side: w1t = W1_f^T (h-major), w2h = 0.5*W2, gcoef[h] = {w1b[h], b1[h]}
// ---------------------------------------------------------------------------
__global__ __launch_bounds__(256) void prep_kernel(
    const float* __restrict__ z, const float* __restrict__ Wz,
    const float* __restrict__ bz, const float* __restrict__ W1,
    const float* __restrict__ b1, const float* __restrict__ W2,
    const float* __restrict__ b2,
    float* __restrict__ A, float* __restrict__ SA2w,
    float* __restrict__ w2h, float* __restrict__ w1t,
    float* __restrict__ gcoef)
{
    __shared__ float pz[2][Hh];
    __shared__ float ps[2][Hh];
    const int t  = threadIdx.x;
    const int h  = t & (Hh - 1);
    const int bb = t >> 7;
    const int b  = blockIdx.x * 2 + bb;

    float v = bz[h];
#pragma unroll
    for (int c = 0; c < Ll; ++c)
        v = fmaf(z[b * Ll + c], Wz[c * Hh + h], v);
    pz[bb][h] = fmaxf(v, 0.f);
    __syncthreads();

    float a = 0.f;
#pragma unroll
    for (int k = 0; k < Hh; ++k)
        a = fmaf(pz[bb][k], W1[k * Hh + h], a);
    A[b * Hh + h] = a;
    ps[bb][h] = 0.5f * W2[h] * a;
    __syncthreads();

    if (h == 0) {
        float s = b2[0];
        for (int k = 0; k < Hh; ++k) s += ps[bb][k];
        SA2w[b] = s;
    }

    // side work (each of 32 blocks handles 4 h-columns)
    if (t < 128) {
        const int h2 = blockIdx.x * 4 + (t >> 5);
        const int c  = t & 31;
        w1t[h2 * Cc + c] = W1[(Hh + c) * Hh + h2];
    }
    if (t < 4) {
        const int h2 = blockIdx.x * 4 + t;
        w2h[h2] = 0.5f * W2[h2];
        gcoef[2 * h2 + 0] = W1[(Hh + Cc) * Hh + h2];
        gcoef[2 * h2 + 1] = b1[h2];
    }
}

// ---------------------------------------------------------------------------
// main: out[b,o] = SA2w[b] + sum_h w2h[h]*g[o,h] + sum_h w2h[h]*|A[b,h]+g[o,h]|
//   (w*relu(x) = 0.5w*x + 0.5w*|x|, exact; b2 folded into SA2w)
// 1024 thr = 16 waves, 256 blocks (1/CU). lane = o throughout.
// PIPE BUDGET (per block): VALU ~1400/thread (per-SIMD pipe), LDS ~640 b32
// (per-CU pipe), SMEM small. NO broadcast LDS reads: g per-lane VGPRs,
// A/w2/w1t via uniform s_load consumed as SGPR operands.
// ---------------------------------------------------------------------------
__global__ __launch_bounds__(NT) void main_kernel(
    const float* __restrict__ A,  const float* __restrict__ SA2w,
    const float* __restrict__ fe, const float* __restrict__ fb,
    const float* __restrict__ w2h, const float* __restrict__ w1t,
    const float* __restrict__ gcoef, float* __restrict__ out)
{
    __shared__ float g_s[Hh][TOo];      // 32 KB; all accesses per-lane: no conflicts
    __shared__ float part[4][Bb][TOo];  // 64 KB

    const int t    = threadIdx.x;
    const int o0   = blockIdx.x * TOo;
    const int lane = t & 63;
    const int wave = __builtin_amdgcn_readfirstlane(t >> 6);  // uniform SGPR

    // --- G phase: wave computes h in [8*wave, 8*wave+8) for all 64 o ---
    {
        float4 fer[8];
        const float4* fep = (const float4*)(fe + (o0 + lane) * Cc);
#pragma unroll
        for (int k = 0; k < 8; ++k) fer[k] = fep[k];   // L1-hot across waves
        const float fbv = fb[o0 + lane];
        const int hG0 = wave * 8;
#pragma unroll
        for (int j = 0; j < 8; ++j) {
            const int h = hG0 + j;
            const float* __restrict__ wt = w1t + h * Cc;          // uniform -> s_load
            float g = fmaf(fbv, gcoef[2 * h + 0], gcoef[2 * h + 1]); // uniform
#pragma unroll
            for (int k = 0; k < 8; ++k) {
                g = fmaf(fer[k].x, wt[4 * k + 0], g);  // V*S+V: 1 SGPR/inst
                g = fmaf(fer[k].y, wt[4 * k + 1], g);
                g = fmaf(fer[k].z, wt[4 * k + 2], g);
                g = fmaf(fer[k].w, wt[4 * k + 3], g);
            }
            g_s[h][lane] = g;                          // per-lane: conflict-free
        }
    }
    __syncthreads();

    // --- inner: wave = (h-slice hh, b-group bg); g + w2 in VGPRs ---
    const int hh = wave & 3, bg = wave >> 2;
    const int h0 = hh * 32,  b0 = bg * 16;

    float gv[32];
#pragma unroll
    for (int k = 0; k < 32; ++k)
        gv[k] = g_s[h0 + k][lane];                     // per-lane: conflict-free

    float w2v[32];
#pragma unroll
    for (int k = 0; k < 32; ++k)
        w2v[k] = w2h[h0 + k];                          // uniform s_load

    float sg = 0.f;
#pragma unroll
    for (int k = 0; k < 32; ++k)
        sg = fmaf(w2v[k], gv[k], sg);

    float acc[16];
#pragma unroll
    for (int bi = 0; bi < 16; ++bi) acc[bi] = sg;

    // 16 independent chains; A rows via uniform s_load (hoisted across chains)
#pragma unroll
    for (int bi = 0; bi < 16; ++bi) {
        const float* __restrict__ Ab = A + (b0 + bi) * Hh + h0;   // uniform
        float a = acc[bi];
#pragma unroll
        for (int k = 0; k < 32; ++k)
            a = fmaf(__builtin_fabsf(Ab[k] + gv[k]), w2v[k], a);  // add: V+S, fma: 1 V-src
        acc[bi] = a;
    }

#pragma unroll
    for (int bi = 0; bi < 16; ++bi)
        part[hh][b0 + bi][lane] = acc[bi];             // per-lane: conflict-free
    __syncthreads();

    // --- uniform combine: each wave handles 4 b ---
#pragma unroll
    for (int q = 0; q < 4; ++q) {
        const int b = wave * 4 + q;
        const float r = part[0][b][lane] + part[1][b][lane]
                      + part[2][b][lane] + part[3][b][lane];
        out[b * Oo + o0 + lane] = r + SA2w[b];         // coalesced 256 B
    }
}

extern "C" void kernel_launch(void* const* d_in, const int* in_sizes, int n_in,
                              void* d_out, int out_size, void* d_ws, size_t ws_size,
                              hipStream_t stream) {
    (void)in_sizes; (void)n_in; (void)out_size; (void)ws_size;
    const float* z   = (const float*)d_in[0];   // (64,32)
    const float* fe  = (const float*)d_in[1];   // (16384,32)
    const float* fb  = (const float*)d_in[2];   // (16384,1)
    const float* Wz  = (const float*)d_in[3];   // (32,128)
    const float* bz  = (const float*)d_in[4];   // (128,)
    const float* W1  = (const float*)d_in[5];   // (161,128)
    const float* b1  = (const float*)d_in[6];   // (128,)
    const float* W2  = (const float*)d_in[7];   // (128,1)
    const float* b2  = (const float*)d_in[8];   // (1,)
    float* out   = (float*)d_out;               // (64,16384)
    float* A     = (float*)d_ws;                // 8192
    float* SA2w  = A + Bb * Hh;                 // 64
    float* w2h   = SA2w + Bb;                   // 128
    float* w1t   = w2h + Hh;                    // 4096
    float* gcoef = w1t + Hh * Cc;               // 256

    prep_kernel<<<Bb / 2, 256, 0, stream>>>(z, Wz, bz, W1, b1, W2, b2,
                                            A, SA2w, w2h, w1t, gcoef);
    main_kernel<<<Oo / TOo, NT, 0, stream>>>(A, SA2w, fe, fb, w2h, w1t,
                                             gcoef, out);
}